// Round 1
// 638.505 us; speedup vs baseline: 1.0721x; 1.0721x over previous
//
#include <hip/hip_runtime.h>
#include <hip/hip_bf16.h>
#include <stdint.h>

#define K_DIM 4096
#define N_DIM 11008
#define BM 256
#define BN 128
#define NT (K_DIM / 64)   // 64 K-tiles of BK=64

typedef _Float16 half8 __attribute__((ext_vector_type(8)));
typedef _Float16 half2v __attribute__((ext_vector_type(2)));
typedef float floatx4 __attribute__((ext_vector_type(4)));

typedef const uint32_t __attribute__((address_space(1)))* gas_u32p;
typedef uint32_t __attribute__((address_space(3)))* las_u32p;

// async global->LDS, 16B per lane; LDS dest = wave-uniform base + lane*16.
__device__ __forceinline__ void glds16(const void* g, void* l) {
    __builtin_amdgcn_global_load_lds((gas_u32p)g, (las_u32p)l, 16, 0, 0);
}

// ---- magic-number int4 dequant, packed-fp16 math ----
// (w>>s)&0x000F000F | 0x64006400 == fp16x2 {1024+q_lo, 1024+q_hi} EXACTLY.
// pk_sub 1032 -> q-8 exact (small ints); pk_mul s -> single fp16 rounding.
// Bit-identical to the previous validated fp32-path dequant ((q-8)*s with
// one rounding).  NOTE: emits nibbles in order [0,4,1,5,2,6,3,7] per word;
// A is pre-permuted identically in cvt_kernel so MFMA dot products match.
__device__ __forceinline__ half8 dequant_word_pk(uint32_t w, half2v s2) {
    const uint32_t M = 0x000F000Fu;
    const uint32_t B = 0x64006400u;
    union { uint32_t u; half2v h; } t0, t1, t2, t3;
    t0.u = (w & M) | B;
    t1.u = ((w >> 4) & M) | B;
    t2.u = ((w >> 8) & M) | B;
    t3.u = ((w >> 12) & M) | B;
    const half2v off = {(_Float16)1032.0f, (_Float16)1032.0f};
    union { half8 h8; half2v h2[4]; } o;
    o.h2[0] = (t0.h - off) * s2;   // q0, q4
    o.h2[1] = (t1.h - off) * s2;   // q1, q5
    o.h2[2] = (t2.h - off) * s2;   // q2, q6
    o.h2[3] = (t3.h - off) * s2;   // q3, q7
    return o.h8;
}

// Old scalar dequant (kept for the validated direct fallback, natural k-order)
__device__ __forceinline__ half8 dequant_word_f16(uint32_t w, float s) {
    half8 r;
    #pragma unroll
    for (int j = 0; j < 8; ++j) {
        int q = (int)((w >> (4 * j)) & 0xFu);
        r[j] = (_Float16)((float)(q - 8) * s);
    }
    return r;
}

// ---------------- pre-pass: X fp32 -> fp16 (exact), k-permuted ----------------
// Within each 8-elem k-chunk, position e holds source k = [0,4,1,5,2,6,3,7][e]
// to match dequant_word_pk's nibble emission order.
__global__ __launch_bounds__(256)
void cvt_kernel(const float* __restrict__ X, _Float16* __restrict__ Xh) {
    size_t idx = (size_t)blockIdx.x * 256 + threadIdx.x;   // 8 elts/thread
    size_t base = idx * 8;
    float4 a = *(const float4*)(X + base);
    float4 b = *(const float4*)(X + base + 4);
    half8 h;
    h[0] = (_Float16)a.x; h[1] = (_Float16)b.x;
    h[2] = (_Float16)a.y; h[3] = (_Float16)b.y;
    h[4] = (_Float16)a.z; h[5] = (_Float16)b.z;
    h[6] = (_Float16)a.w; h[7] = (_Float16)b.w;
    *(half8*)(Xh + base) = h;
}

// ---------------- main: LDS-staged A (fp16), register-dequant B ----------------
__global__ __launch_bounds__(256, 2)
void qgemm_lds(const _Float16* __restrict__ Xh,
               const int* __restrict__ Wp,
               const float* __restrict__ Sc,
               const float* __restrict__ Bias,
               float* __restrict__ Out)
{
    // A tile 256x64 fp16 = 32 KB, stored as XOR-swizzled 16B chunks:
    // chunk (row, c) lands at slot row*8 + (c ^ (row&7)).
    __shared__ half8 As[BM * 8];   // 2048 chunks * 16B

    const int tid = threadIdx.x;
    const int m0 = blockIdx.x * BM;          // 16 m-blocks (x mod 8 -> XCD affinity)
    const int n0 = blockIdx.y * BN;          // 86 n-blocks

    const int lane = tid & 63;
    const int wid  = tid >> 6;
    const int wm   = wid >> 1;               // m half (128 rows)
    const int wn   = wid & 1;                // n half (64 cols)
    const int q    = lane >> 4;              // quad 0..3
    const int tt   = lane & 15;

    // staging: thread t, iter i stages global chunk c of row i*32 + (t>>3)
    // into LDS slot i*256 + t;  c = (t&7) ^ ((t>>3)&7)  (constant over i).
    const int arow = tid >> 3;
    const int ac   = (tid & 7) ^ (arow & 7);
    const _Float16* aSrc = Xh + (size_t)(m0 + arow) * K_DIM + ac * 8;

    // B fragment: lane's word = packed[kt*8 + ks*4 + q][ncol + j*16]
    const int ncol = n0 + wn * 64 + tt;
    const int* bPtr = Wp + (size_t)q * N_DIM + ncol;
    const float* scPtr = Sc + ncol;

    floatx4 acc[8][4];
    #pragma unroll
    for (int i = 0; i < 8; ++i)
        #pragma unroll
        for (int j = 0; j < 4; ++j)
            acc[i][j] = floatx4{0.f, 0.f, 0.f, 0.f};

    // fragment read bases (bytes): row = wm*128 + i*16 + tt, chunk = ks*4+q,
    // swizzled slot = (ks*4+q) ^ (tt&7)  (row&7 == tt&7 here).
    const int x7  = tt & 7;
    const int rb0 = tt * 128 + ((0 * 4 + q) ^ x7) * 16;
    const int rb1 = tt * 128 + ((1 * 4 + q) ^ x7) * 16;
    const char* asBase = (const char*)As + wm * 16384;

    // prologue: group-0 scales (fp16, packed) + tile-0 words
    half2v s2[4], sn2[4];
    #pragma unroll
    for (int j = 0; j < 4; ++j) {
        _Float16 sh = (_Float16)scPtr[j * 16];   // exact: fp32 was promoted fp16
        s2[j] = (half2v){sh, sh};
    }
    uint32_t wv[8];
    #pragma unroll
    for (int ks = 0; ks < 2; ++ks)
        #pragma unroll
        for (int j = 0; j < 4; ++j)
            wv[ks * 4 + j] = (uint32_t)bPtr[(size_t)(ks * 4) * N_DIM + j * 16];

    for (int kt = 0; kt < NT; ++kt) {
        // commit prefetched scales at group boundary (uniform branch)
        if (kt > 0 && (kt & 1) == 0) {
            #pragma unroll
            for (int j = 0; j < 4; ++j) s2[j] = sn2[j];
        }

        // issue A DMA for this tile (8 x 16B per thread = 32 KB)
        #pragma unroll
        for (int i = 0; i < 8; ++i)
            glds16(aSrc + (size_t)i * 32 * K_DIM + kt * 64,
                   (char*)As + (size_t)(i * 256 + tid) * 16);

        // dequant current words (registers only, packed-fp16 magic trick)
        half8 bf[8];
        #pragma unroll
        for (int ks = 0; ks < 2; ++ks)
            #pragma unroll
            for (int j = 0; j < 4; ++j)
                bf[ks * 4 + j] = dequant_word_pk(wv[ks * 4 + j], s2[j]);

        // prefetch next tile's words (+ next group's scales); their drain
        // rides the barrier's vmcnt(0) that the A DMA requires anyway
        if (kt + 1 < NT) {
            const int* bp = bPtr + (size_t)(kt + 1) * 8 * N_DIM;
            #pragma unroll
            for (int ks = 0; ks < 2; ++ks)
                #pragma unroll
                for (int j = 0; j < 4; ++j)
                    wv[ks * 4 + j] = (uint32_t)bp[(size_t)(ks * 4) * N_DIM + j * 16];
            if (kt & 1) {
                const float* sp = scPtr + (size_t)((kt + 1) >> 1) * N_DIM;
                #pragma unroll
                for (int j = 0; j < 4; ++j) {
                    _Float16 sh = (_Float16)sp[j * 16];
                    sn2[j] = (half2v){sh, sh};
                }
            }
        }

        __syncthreads();   // drains vmcnt(0): A DMA (+ B prefetch) complete

        // compute: 2 k-steps x 8 m-tiles x 4 n-tiles = 64 MFMA
        #pragma unroll
        for (int ks = 0; ks < 2; ++ks) {
            const int rb = ks ? rb1 : rb0;
            #pragma unroll
            for (int i = 0; i < 8; ++i) {
                half8 af = *(const half8*)(asBase + rb + i * 2048);
                #pragma unroll
                for (int j = 0; j < 4; ++j)
                    acc[i][j] = __builtin_amdgcn_mfma_f32_16x16x32_f16(
                        af, bf[ks * 4 + j], acc[i][j], 0, 0, 0);
            }
        }

        __syncthreads();   // all reads done before next tile's DMA overwrites
    }

    // epilogue: C/D layout col=lane&15, row=(lane>>4)*4+r; fp32 out + bias
    #pragma unroll
    for (int j = 0; j < 4; ++j) {
        const int n = ncol + j * 16;
        const float bv = Bias[n];
        #pragma unroll
        for (int i = 0; i < 8; ++i) {
            const int mrow = m0 + wm * 128 + i * 16 + q * 4;
            #pragma unroll
            for (int r = 0; r < 4; ++r)
                Out[(size_t)(mrow + r) * N_DIM + n] = acc[i][j][r] + bv;
        }
    }
}

// ---------------- fallback (R4, validated): direct-from-global A ----------------
// Self-consistent natural k-order on both sides; unchanged.
__global__ __launch_bounds__(256, 2)
void qgemm_direct(const float* __restrict__ X,
                  const int* __restrict__ Wp,
                  const float* __restrict__ Sc,
                  const float* __restrict__ Bias,
                  float* __restrict__ Out)
{
    const int tid = threadIdx.x;
    const int m0 = blockIdx.x * BM;
    const int n0 = blockIdx.y * BN;
    const int lane = tid & 63;
    const int wid  = tid >> 6;
    const int wm   = wid >> 1;
    const int wn   = wid & 1;
    const int q    = lane >> 4;
    const int tt   = lane & 15;

    const int ncol = n0 + wn * 64 + tt;
    const int* bPtr = Wp + (size_t)q * N_DIM + ncol;
    const float* scPtr = Sc + ncol;
    const float* aBase = X + (size_t)(m0 + wm * 128 + tt) * K_DIM + q * 8;

    floatx4 acc[8][4];
    #pragma unroll
    for (int i = 0; i < 8; ++i)
        #pragma unroll
        for (int j = 0; j < 4; ++j)
            acc[i][j] = floatx4{0.f, 0.f, 0.f, 0.f};

    float s[4];
    for (int kt = 0; kt < NT; ++kt) {
        if ((kt & 1) == 0) {
            const float* sp = scPtr + (size_t)(kt >> 1) * N_DIM;
            #pragma unroll
            for (int j = 0; j < 4; ++j) s[j] = sp[j * 16];
        }
        const int* bp = bPtr + (size_t)kt * 8 * N_DIM;
        uint32_t wv[8];
        #pragma unroll
        for (int ks = 0; ks < 2; ++ks)
            #pragma unroll
            for (int j = 0; j < 4; ++j)
                wv[ks * 4 + j] = (uint32_t)bp[(size_t)(ks * 4) * N_DIM + j * 16];
        half8 bf[8];
        #pragma unroll
        for (int ks = 0; ks < 2; ++ks)
            #pragma unroll
            for (int j = 0; j < 4; ++j)
                bf[ks * 4 + j] = dequant_word_f16(wv[ks * 4 + j], s[j]);
        #pragma unroll
        for (int ks = 0; ks < 2; ++ks) {
            const size_t ko = (size_t)(kt * 64 + ks * 32);
            #pragma unroll
            for (int i = 0; i < 8; ++i) {
                const float* ap = aBase + (size_t)i * 16 * K_DIM + ko;
                float4 lo = *(const float4*)ap;
                float4 hi = *(const float4*)(ap + 4);
                half8 af;
                af[0] = (_Float16)lo.x; af[1] = (_Float16)lo.y;
                af[2] = (_Float16)lo.z; af[3] = (_Float16)lo.w;
                af[4] = (_Float16)hi.x; af[5] = (_Float16)hi.y;
                af[6] = (_Float16)hi.z; af[7] = (_Float16)hi.w;
                #pragma unroll
                for (int j = 0; j < 4; ++j)
                    acc[i][j] = __builtin_amdgcn_mfma_f32_16x16x32_f16(
                        af, bf[ks * 4 + j], acc[i][j], 0, 0, 0);
            }
        }
    }
    #pragma unroll
    for (int j = 0; j < 4; ++j) {
        const int n = ncol + j * 16;
        const float bv = Bias[n];
        #pragma unroll
        for (int i = 0; i < 8; ++i) {
            const int mrow = m0 + wm * 128 + i * 16 + q * 4;
            #pragma unroll
            for (int r = 0; r < 4; ++r)
                Out[(size_t)(mrow + r) * N_DIM + n] = acc[i][j][r] + bv;
        }
    }
}

extern "C" void kernel_launch(void* const* d_in, const int* in_sizes, int n_in,
                              void* d_out, int out_size, void* d_ws, size_t ws_size,
                              hipStream_t stream) {
    (void)in_sizes; (void)n_in; (void)out_size;
    const float* X    = (const float*)d_in[0];
    const int*   Wp   = (const int*)d_in[1];
    const float* Sc   = (const float*)d_in[2];
    const float* Bias = (const float*)d_in[3];
    float*       Out  = (float*)d_out;

    dim3 grid(4096 / BM, N_DIM / BN);   // (16, 86)
    const size_t needed = (size_t)4096 * K_DIM * sizeof(_Float16);  // 33.5 MB

    if (ws_size >= needed) {
        _Float16* Xh = (_Float16*)d_ws;
        cvt_kernel<<<(4096 * K_DIM) / (256 * 8), 256, 0, stream>>>(X, Xh);
        qgemm_lds<<<grid, 256, 0, stream>>>(Xh, Wp, Sc, Bias, Out);
    } else {
        qgemm_direct<<<grid, 256, 0, stream>>>(X, Wp, Sc, Bias, Out);
    }
}

// Round 2
// 613.026 us; speedup vs baseline: 1.1166x; 1.0416x over previous
//
#include <hip/hip_runtime.h>
#include <hip/hip_bf16.h>
#include <stdint.h>

#define K_DIM 4096
#define N_DIM 11008
#define BM 256
#define BN 128
#define NT (K_DIM / 64)   // 64 K-tiles of BK=64

typedef _Float16 half8 __attribute__((ext_vector_type(8)));
typedef _Float16 half2v __attribute__((ext_vector_type(2)));
typedef float floatx4 __attribute__((ext_vector_type(4)));

typedef const uint32_t __attribute__((address_space(1)))* gas_u32p;
typedef uint32_t __attribute__((address_space(3)))* las_u32p;

// async global->LDS, 16B per lane; LDS dest = wave-uniform base + lane*16.
__device__ __forceinline__ void glds16(const void* g, void* l) {
    __builtin_amdgcn_global_load_lds((gas_u32p)g, (las_u32p)l, 16, 0, 0);
}

// ---- magic-number int4 dequant, packed-fp16 math (validated R1) ----
// (w>>s)&0x000F000F | 0x64006400 == fp16x2 {1024+q_lo, 1024+q_hi} EXACTLY.
// pk_sub 1032 -> q-8 exact; pk_mul s -> single fp16 rounding.
// Emits nibbles in order [0,4,1,5,2,6,3,7]; A pre-permuted to match.
__device__ __forceinline__ half8 dequant_word_pk(uint32_t w, half2v s2) {
    const uint32_t M = 0x000F000Fu;
    const uint32_t B = 0x64006400u;
    union { uint32_t u; half2v h; } t0, t1, t2, t3;
    t0.u = (w & M) | B;
    t1.u = ((w >> 4) & M) | B;
    t2.u = ((w >> 8) & M) | B;
    t3.u = ((w >> 12) & M) | B;
    const half2v off = {(_Float16)1032.0f, (_Float16)1032.0f};
    union { half8 h8; half2v h2[4]; } o;
    o.h2[0] = (t0.h - off) * s2;   // q0, q4
    o.h2[1] = (t1.h - off) * s2;   // q1, q5
    o.h2[2] = (t2.h - off) * s2;   // q2, q6
    o.h2[3] = (t3.h - off) * s2;   // q3, q7
    return o.h8;
}

// Old scalar dequant (kept for the validated direct fallback, natural k-order)
__device__ __forceinline__ half8 dequant_word_f16(uint32_t w, float s) {
    half8 r;
    #pragma unroll
    for (int j = 0; j < 8; ++j) {
        int q = (int)((w >> (4 * j)) & 0xFu);
        r[j] = (_Float16)((float)(q - 8) * s);
    }
    return r;
}

// ---------------- pre-pass: X fp32 -> fp16 (exact), k-permuted ----------------
// Position e of each 8-chunk holds source k = [0,4,1,5,2,6,3,7][e].
__global__ __launch_bounds__(256)
void cvt_kernel(const float* __restrict__ X, _Float16* __restrict__ Xh) {
    size_t idx = (size_t)blockIdx.x * 256 + threadIdx.x;   // 8 elts/thread
    size_t base = idx * 8;
    float4 a = *(const float4*)(X + base);
    float4 b = *(const float4*)(X + base + 4);
    half8 h;
    h[0] = (_Float16)a.x; h[1] = (_Float16)b.x;
    h[2] = (_Float16)a.y; h[3] = (_Float16)b.y;
    h[4] = (_Float16)a.z; h[5] = (_Float16)b.z;
    h[6] = (_Float16)a.w; h[7] = (_Float16)b.w;
    *(half8*)(Xh + base) = h;
}

// ------------- main: double-buffered LDS A, counted vmcnt, raw barrier -------------
__global__ __launch_bounds__(256, 2)
void qgemm_lds(const _Float16* __restrict__ Xh,
               const int* __restrict__ Wp,
               const float* __restrict__ Sc,
               const float* __restrict__ Bias,
               float* __restrict__ Out)
{
    // A tile 256x64 fp16 = 32 KB per buffer, double-buffered (64 KB total).
    // XOR-swizzled 16B chunks: chunk (row, c) -> slot row*8 + (c ^ (row&7)).
    __shared__ half8 As[2][BM * 8];

    const int tid = threadIdx.x;
    const int m0 = blockIdx.x * BM;          // 16 m-blocks
    const int n0 = blockIdx.y * BN;          // 86 n-blocks

    const int lane = tid & 63;
    const int wid  = tid >> 6;
    const int wm   = wid >> 1;               // m half (128 rows)
    const int wn   = wid & 1;                // n half (64 cols)
    const int q    = lane >> 4;              // quad 0..3
    const int tt   = lane & 15;

    // staging: thread t, iter i stages global chunk c of row i*32 + (t>>3)
    // into LDS slot i*256 + t;  c = (t&7) ^ ((t>>3)&7).
    const int arow = tid >> 3;
    const int ac   = (tid & 7) ^ (arow & 7);
    const _Float16* aSrc = Xh + (size_t)(m0 + arow) * K_DIM + ac * 8;

    // B fragment: lane's word = packed[kt*8 + ks*4 + q][ncol + j*16]
    const int ncol = n0 + wn * 64 + tt;
    const int* bPtr = Wp + (size_t)q * N_DIM + ncol;
    const float* scPtr = Sc + ncol;

    floatx4 acc[8][4];
    #pragma unroll
    for (int i = 0; i < 8; ++i)
        #pragma unroll
        for (int j = 0; j < 4; ++j)
            acc[i][j] = floatx4{0.f, 0.f, 0.f, 0.f};

    // fragment read bases (bytes): row = wm*128 + i*16 + tt, chunk = ks*4+q,
    // swizzled slot = (ks*4+q) ^ (tt&7)  (row&7 == tt&7 here).
    const int x7  = tt & 7;
    const int rb0 = tt * 128 + ((0 * 4 + q) ^ x7) * 16;
    const int rb1 = tt * 128 + ((1 * 4 + q) ^ x7) * 16;

    // ---- prologue: A-DMA tile0 -> buf0, then scales + tile-0 B words ----
    #pragma unroll
    for (int i = 0; i < 8; ++i)
        glds16(aSrc + (size_t)i * 32 * K_DIM,
               (char*)As[0] + (size_t)(i * 256 + tid) * 16);
    __builtin_amdgcn_sched_barrier(0);

    half2v s2[4], sn2[4];
    #pragma unroll
    for (int j = 0; j < 4; ++j) {
        _Float16 sh = (_Float16)scPtr[j * 16];   // exact: fp32 was promoted fp16
        s2[j] = (half2v){sh, sh};
    }
    uint32_t wv[8];
    #pragma unroll
    for (int ks = 0; ks < 2; ++ks)
        #pragma unroll
        for (int j = 0; j < 4; ++j)
            wv[ks * 4 + j] = (uint32_t)bPtr[(size_t)(ks * 4) * N_DIM + j * 16];

    // one-time full drain: buf0 ready for all waves after this barrier
    asm volatile("s_waitcnt vmcnt(0)" ::: "memory");
    __builtin_amdgcn_s_barrier();
    __builtin_amdgcn_sched_barrier(0);

    for (int kt = 0; kt < NT; ++kt) {
        const int cur = kt & 1;

        // commit prefetched scales at group boundary (uniform branch)
        if (kt > 0 && (kt & 1) == 0) {
            #pragma unroll
            for (int j = 0; j < 4; ++j) s2[j] = sn2[j];
        }

        // issue A DMA for NEXT tile into the other buffer (8 x 16B / thread)
        if (kt + 1 < NT) {
            #pragma unroll
            for (int i = 0; i < 8; ++i)
                glds16(aSrc + (size_t)i * 32 * K_DIM + (kt + 1) * 64,
                       (char*)As[cur ^ 1] + (size_t)(i * 256 + tid) * 16);
        }
        __builtin_amdgcn_sched_barrier(0);   // pin DMA before later loads

        // dequant current words (registers only; compiler inserts counted
        // vmcnt for wv here, leaving the A-DMA in flight)
        half8 bf[8];
        #pragma unroll
        for (int ks = 0; ks < 2; ++ks)
            #pragma unroll
            for (int j = 0; j < 4; ++j)
                bf[ks * 4 + j] = dequant_word_pk(wv[ks * 4 + j], s2[j]);

        // prefetch next tile's B words (+ next group's scales)
        if (kt + 1 < NT) {
            const int* bp = bPtr + (size_t)(kt + 1) * 8 * N_DIM;
            #pragma unroll
            for (int ks = 0; ks < 2; ++ks)
                #pragma unroll
                for (int j = 0; j < 4; ++j)
                    wv[ks * 4 + j] = (uint32_t)bp[(size_t)(ks * 4) * N_DIM + j * 16];
            if (kt & 1) {
                const float* sp = scPtr + (size_t)((kt + 1) >> 1) * N_DIM;
                #pragma unroll
                for (int j = 0; j < 4; ++j) {
                    _Float16 sh = (_Float16)sp[j * 16];
                    sn2[j] = (half2v){sh, sh};
                }
            }
        }

        // compute from current buffer: 2 k-steps x 8 m x 4 n = 64 MFMA
        const char* ab = (const char*)As[cur] + wm * 16384;
        #pragma unroll
        for (int ks = 0; ks < 2; ++ks) {
            const int rb = ks ? rb1 : rb0;
            #pragma unroll
            for (int i = 0; i < 8; ++i) {
                half8 af = *(const half8*)(ab + rb + i * 2048);
                #pragma unroll
                for (int j = 0; j < 4; ++j)
                    acc[i][j] = __builtin_amdgcn_mfma_f32_16x16x32_f16(
                        af, bf[ks * 4 + j], acc[i][j], 0, 0, 0);
            }
        }

        // tail sync: wait for OWN next-tile A-DMA (counted — the 8 B-word
        // loads, +4 scale loads on odd kt, issued after it stay in flight),
        // then raw barrier. After the barrier every wave's DMA into
        // As[cur^1] is complete and all reads of As[cur] are done.
        if (kt + 1 < NT) {
            if (kt & 1) { asm volatile("s_waitcnt vmcnt(12)" ::: "memory"); }
            else        { asm volatile("s_waitcnt vmcnt(8)"  ::: "memory"); }
            __builtin_amdgcn_s_barrier();
            __builtin_amdgcn_sched_barrier(0);
        }
    }

    // epilogue: C/D layout col=lane&15, row=(lane>>4)*4+r; fp32 out + bias
    #pragma unroll
    for (int j = 0; j < 4; ++j) {
        const int n = ncol + j * 16;
        const float bv = Bias[n];
        #pragma unroll
        for (int i = 0; i < 8; ++i) {
            const int mrow = m0 + wm * 128 + i * 16 + q * 4;
            #pragma unroll
            for (int r = 0; r < 4; ++r)
                Out[(size_t)(mrow + r) * N_DIM + n] = acc[i][j][r] + bv;
        }
    }
}

// ---------------- fallback (R4, validated): direct-from-global A ----------------
__global__ __launch_bounds__(256, 2)
void qgemm_direct(const float* __restrict__ X,
                  const int* __restrict__ Wp,
                  const float* __restrict__ Sc,
                  const float* __restrict__ Bias,
                  float* __restrict__ Out)
{
    const int tid = threadIdx.x;
    const int m0 = blockIdx.x * BM;
    const int n0 = blockIdx.y * BN;
    const int lane = tid & 63;
    const int wid  = tid >> 6;
    const int wm   = wid >> 1;
    const int wn   = wid & 1;
    const int q    = lane >> 4;
    const int tt   = lane & 15;

    const int ncol = n0 + wn * 64 + tt;
    const int* bPtr = Wp + (size_t)q * N_DIM + ncol;
    const float* scPtr = Sc + ncol;
    const float* aBase = X + (size_t)(m0 + wm * 128 + tt) * K_DIM + q * 8;

    floatx4 acc[8][4];
    #pragma unroll
    for (int i = 0; i < 8; ++i)
        #pragma unroll
        for (int j = 0; j < 4; ++j)
            acc[i][j] = floatx4{0.f, 0.f, 0.f, 0.f};

    float s[4];
    for (int kt = 0; kt < NT; ++kt) {
        if ((kt & 1) == 0) {
            const float* sp = scPtr + (size_t)(kt >> 1) * N_DIM;
            #pragma unroll
            for (int j = 0; j < 4; ++j) s[j] = sp[j * 16];
        }
        const int* bp = bPtr + (size_t)kt * 8 * N_DIM;
        uint32_t wv[8];
        #pragma unroll
        for (int ks = 0; ks < 2; ++ks)
            #pragma unroll
            for (int j = 0; j < 4; ++j)
                wv[ks * 4 + j] = (uint32_t)bp[(size_t)(ks * 4) * N_DIM + j * 16];
        half8 bf[8];
        #pragma unroll
        for (int ks = 0; ks < 2; ++ks)
            #pragma unroll
            for (int j = 0; j < 4; ++j)
                bf[ks * 4 + j] = dequant_word_f16(wv[ks * 4 + j], s[j]);
        #pragma unroll
        for (int ks = 0; ks < 2; ++ks) {
            const size_t ko = (size_t)(kt * 64 + ks * 32);
            #pragma unroll
            for (int i = 0; i < 8; ++i) {
                const float* ap = aBase + (size_t)i * 16 * K_DIM + ko;
                float4 lo = *(const float4*)ap;
                float4 hi = *(const float4*)(ap + 4);
                half8 af;
                af[0] = (_Float16)lo.x; af[1] = (_Float16)lo.y;
                af[2] = (_Float16)lo.z; af[3] = (_Float16)lo.w;
                af[4] = (_Float16)hi.x; af[5] = (_Float16)hi.y;
                af[6] = (_Float16)hi.z; af[7] = (_Float16)hi.w;
                #pragma unroll
                for (int j = 0; j < 4; ++j)
                    acc[i][j] = __builtin_amdgcn_mfma_f32_16x16x32_f16(
                        af, bf[ks * 4 + j], acc[i][j], 0, 0, 0);
            }
        }
    }
    #pragma unroll
    for (int j = 0; j < 4; ++j) {
        const int n = ncol + j * 16;
        const float bv = Bias[n];
        #pragma unroll
        for (int i = 0; i < 8; ++i) {
            const int mrow = m0 + wm * 128 + i * 16 + q * 4;
            #pragma unroll
            for (int r = 0; r < 4; ++r)
                Out[(size_t)(mrow + r) * N_DIM + n] = acc[i][j][r] + bv;
        }
    }
}

extern "C" void kernel_launch(void* const* d_in, const int* in_sizes, int n_in,
                              void* d_out, int out_size, void* d_ws, size_t ws_size,
                              hipStream_t stream) {
    (void)in_sizes; (void)n_in; (void)out_size;
    const float* X    = (const float*)d_in[0];
    const int*   Wp   = (const int*)d_in[1];
    const float* Sc   = (const float*)d_in[2];
    const float* Bias = (const float*)d_in[3];
    float*       Out  = (float*)d_out;

    dim3 grid(4096 / BM, N_DIM / BN);   // (16, 86)
    const size_t needed = (size_t)4096 * K_DIM * sizeof(_Float16);  // 33.5 MB

    if (ws_size >= needed) {
        _Float16* Xh = (_Float16*)d_ws;
        cvt_kernel<<<(4096 * K_DIM) / (256 * 8), 256, 0, stream>>>(X, Xh);
        qgemm_lds<<<grid, 256, 0, stream>>>(Xh, Wp, Sc, Bias, Out);
    } else {
        qgemm_direct<<<grid, 256, 0, stream>>>(X, Wp, Sc, Bias, Out);
    }
}

// Round 4
// 587.293 us; speedup vs baseline: 1.1655x; 1.0438x over previous
//
#include <hip/hip_runtime.h>
#include <hip/hip_bf16.h>
#include <stdint.h>

#define K_DIM 4096
#define N_DIM 11008
#define BM 256
#define BN 128
#define NT (K_DIM / 64)   // 64 K-tiles of BK=64

typedef _Float16 half8 __attribute__((ext_vector_type(8)));
typedef _Float16 half2v __attribute__((ext_vector_type(2)));
typedef float floatx4 __attribute__((ext_vector_type(4)));

typedef const uint32_t __attribute__((address_space(1)))* gas_u32p;
typedef uint32_t __attribute__((address_space(3)))* las_u32p;

// async global->LDS, 16B per lane; LDS dest = wave-uniform base + lane*16.
__device__ __forceinline__ void glds16(const void* g, void* l) {
    __builtin_amdgcn_global_load_lds((gas_u32p)g, (las_u32p)l, 16, 0, 0);
}

// ---- magic-number int4 dequant, packed-fp16 math (validated R1) ----
// (w>>s)&0x000F000F | 0x64006400 == fp16x2 {1024+q_lo, 1024+q_hi} EXACTLY.
// pk_sub 1032 -> q-8 exact; pk_mul s -> single fp16 rounding.
// Emits nibbles in order [0,4,1,5,2,6,3,7]; A pre-permuted to match.
__device__ __forceinline__ half8 dequant_word_pk(uint32_t w, half2v s2) {
    const uint32_t M = 0x000F000Fu;
    const uint32_t B = 0x64006400u;
    union { uint32_t u; half2v h; } t0, t1, t2, t3;
    t0.u = (w & M) | B;
    t1.u = ((w >> 4) & M) | B;
    t2.u = ((w >> 8) & M) | B;
    t3.u = ((w >> 12) & M) | B;
    const half2v off = {(_Float16)1032.0f, (_Float16)1032.0f};
    union { half8 h8; half2v h2[4]; } o;
    o.h2[0] = (t0.h - off) * s2;   // q0, q4
    o.h2[1] = (t1.h - off) * s2;   // q1, q5
    o.h2[2] = (t2.h - off) * s2;   // q2, q6
    o.h2[3] = (t3.h - off) * s2;   // q3, q7
    return o.h8;
}

// Old scalar dequant (kept for the validated direct fallback, natural k-order)
__device__ __forceinline__ half8 dequant_word_f16(uint32_t w, float s) {
    half8 r;
    #pragma unroll
    for (int j = 0; j < 8; ++j) {
        int q = (int)((w >> (4 * j)) & 0xFu);
        r[j] = (_Float16)((float)(q - 8) * s);
    }
    return r;
}

// ---------------- pre-pass: X fp32 -> fp16 (exact), k-permuted ----------------
// Position e of each 8-chunk holds source k = [0,4,1,5,2,6,3,7][e].
// X is read once -> non-temporal loads (don't pollute L2/L3); Xh stays cached.
// NOTE: clang's nontemporal builtins need ext_vector types, not HIP float4.
__global__ __launch_bounds__(256)
void cvt_kernel(const float* __restrict__ X, _Float16* __restrict__ Xh) {
    size_t idx = (size_t)blockIdx.x * 256 + threadIdx.x;   // 8 elts/thread
    size_t base = idx * 8;
    floatx4 a = __builtin_nontemporal_load((const floatx4*)(X + base));
    floatx4 b = __builtin_nontemporal_load((const floatx4*)(X + base + 4));
    half8 h;
    h[0] = (_Float16)a[0]; h[1] = (_Float16)b[0];
    h[2] = (_Float16)a[1]; h[3] = (_Float16)b[1];
    h[4] = (_Float16)a[2]; h[5] = (_Float16)b[2];
    h[6] = (_Float16)a[3]; h[7] = (_Float16)b[3];
    *(half8*)(Xh + base) = h;
}

// ------------- main: double-buffered LDS A, counted vmcnt, raw barrier -------------
__global__ __launch_bounds__(256, 2)
void qgemm_lds(const _Float16* __restrict__ Xh,
               const int* __restrict__ Wp,
               const float* __restrict__ Sc,
               const float* __restrict__ Bias,
               float* __restrict__ Out)
{
    // A tile 256x64 fp16 = 32 KB per buffer, double-buffered (64 KB total).
    // XOR-swizzled 16B chunks: chunk (row, c) -> slot row*8 + (c ^ (row&7)).
    __shared__ half8 As[2][BM * 8];

    const int tid = threadIdx.x;

    // XCD-affine remap: dispatch id -> XCD x = bid&7 (round-robin model).
    // XCD x owns m-blocks {2x, 2x+1}; n sweeps. A working set per XCD =
    // 2 tiles * 2 MB = 4 MB = its L2. Bijective: bid = x + 8*(2n + (m&1)).
    const int bid = blockIdx.y * gridDim.x + blockIdx.x;   // 0..1375
    const int xcd = bid & 7;
    const int k_r = bid >> 3;                              // 0..171
    const int m0 = (xcd * 2 + (k_r & 1)) * BM;             // m-block 0..15
    const int n0 = (k_r >> 1) * BN;                        // n-block 0..85

    const int lane = tid & 63;
    const int wid  = tid >> 6;
    const int wm   = wid >> 1;               // m half (128 rows)
    const int wn   = wid & 1;                // n half (64 cols)
    const int q    = lane >> 4;              // quad 0..3
    const int tt   = lane & 15;

    // staging: thread t, iter i stages global chunk c of row i*32 + (t>>3)
    // into LDS slot i*256 + t;  c = (t&7) ^ ((t>>3)&7).
    const int arow = tid >> 3;
    const int ac   = (tid & 7) ^ (arow & 7);
    const _Float16* aSrc = Xh + (size_t)(m0 + arow) * K_DIM + ac * 8;

    // B fragment: lane's word = packed[kt*8 + ks*4 + q][ncol + j*16]
    const int ncol = n0 + wn * 64 + tt;
    const int* bPtr = Wp + (size_t)q * N_DIM + ncol;
    const float* scPtr = Sc + ncol;

    floatx4 acc[8][4];
    #pragma unroll
    for (int i = 0; i < 8; ++i)
        #pragma unroll
        for (int j = 0; j < 4; ++j)
            acc[i][j] = floatx4{0.f, 0.f, 0.f, 0.f};

    // fragment read bases (bytes): row = wm*128 + i*16 + tt, chunk = ks*4+q,
    // swizzled slot = (ks*4+q) ^ (tt&7)  (row&7 == tt&7 here).
    const int x7  = tt & 7;
    const int rb0 = tt * 128 + ((0 * 4 + q) ^ x7) * 16;
    const int rb1 = tt * 128 + ((1 * 4 + q) ^ x7) * 16;

    // ---- prologue: A-DMA tile0 -> buf0, then scales + tile-0 B words ----
    #pragma unroll
    for (int i = 0; i < 8; ++i)
        glds16(aSrc + (size_t)i * 32 * K_DIM,
               (char*)As[0] + (size_t)(i * 256 + tid) * 16);
    __builtin_amdgcn_sched_barrier(0);

    half2v s2[4], sn2[4];
    #pragma unroll
    for (int j = 0; j < 4; ++j) {
        _Float16 sh = (_Float16)scPtr[j * 16];   // exact: fp32 was promoted fp16
        s2[j] = (half2v){sh, sh};
    }
    uint32_t wv[8];
    #pragma unroll
    for (int ks = 0; ks < 2; ++ks)
        #pragma unroll
        for (int j = 0; j < 4; ++j)
            wv[ks * 4 + j] = (uint32_t)bPtr[(size_t)(ks * 4) * N_DIM + j * 16];

    // one-time full drain: buf0 ready for all waves after this barrier
    asm volatile("s_waitcnt vmcnt(0)" ::: "memory");
    __builtin_amdgcn_s_barrier();
    __builtin_amdgcn_sched_barrier(0);

    for (int kt = 0; kt < NT; ++kt) {
        const int cur = kt & 1;

        // commit prefetched scales at group boundary (uniform branch)
        if (kt > 0 && (kt & 1) == 0) {
            #pragma unroll
            for (int j = 0; j < 4; ++j) s2[j] = sn2[j];
        }

        // issue A DMA for NEXT tile into the other buffer (8 x 16B / thread)
        if (kt + 1 < NT) {
            #pragma unroll
            for (int i = 0; i < 8; ++i)
                glds16(aSrc + (size_t)i * 32 * K_DIM + (kt + 1) * 64,
                       (char*)As[cur ^ 1] + (size_t)(i * 256 + tid) * 16);
        }
        __builtin_amdgcn_sched_barrier(0);   // pin DMA before later loads

        // dequant current words (registers only)
        half8 bf[8];
        #pragma unroll
        for (int ks = 0; ks < 2; ++ks)
            #pragma unroll
            for (int j = 0; j < 4; ++j)
                bf[ks * 4 + j] = dequant_word_pk(wv[ks * 4 + j], s2[j]);

        // prefetch next tile's B words (+ next group's scales)
        if (kt + 1 < NT) {
            const int* bp = bPtr + (size_t)(kt + 1) * 8 * N_DIM;
            #pragma unroll
            for (int ks = 0; ks < 2; ++ks)
                #pragma unroll
                for (int j = 0; j < 4; ++j)
                    wv[ks * 4 + j] = (uint32_t)bp[(size_t)(ks * 4) * N_DIM + j * 16];
            if (kt & 1) {
                const float* sp = scPtr + (size_t)((kt + 1) >> 1) * N_DIM;
                #pragma unroll
                for (int j = 0; j < 4; ++j) {
                    _Float16 sh = (_Float16)sp[j * 16];
                    sn2[j] = (half2v){sh, sh};
                }
            }
        }

        // compute from current buffer: 2 k-steps x 8 m x 4 n = 64 MFMA
        const char* ab = (const char*)As[cur] + wm * 16384;
        #pragma unroll
        for (int ks = 0; ks < 2; ++ks) {
            const int rb = ks ? rb1 : rb0;
            #pragma unroll
            for (int i = 0; i < 8; ++i) {
                half8 af = *(const half8*)(ab + rb + i * 2048);
                #pragma unroll
                for (int j = 0; j < 4; ++j)
                    acc[i][j] = __builtin_amdgcn_mfma_f32_16x16x32_f16(
                        af, bf[ks * 4 + j], acc[i][j], 0, 0, 0);
            }
        }

        // tail sync: wait for OWN next-tile A-DMA (counted — the 8 B-word
        // loads, +4 scale loads on odd kt, issued after it stay in flight),
        // then raw barrier.
        if (kt + 1 < NT) {
            if (kt & 1) { asm volatile("s_waitcnt vmcnt(12)" ::: "memory"); }
            else        { asm volatile("s_waitcnt vmcnt(8)"  ::: "memory"); }
            __builtin_amdgcn_s_barrier();
            __builtin_amdgcn_sched_barrier(0);
        }
    }

    // epilogue: C/D layout col=lane&15, row=(lane>>4)*4+r; fp32 out + bias.
    // Non-temporal stores: Out (181 MB/pass) is write-once — keep it from
    // flushing Xh out of L2/L3.
    #pragma unroll
    for (int j = 0; j < 4; ++j) {
        const int n = ncol + j * 16;
        const float bv = Bias[n];
        #pragma unroll
        for (int i = 0; i < 8; ++i) {
            const int mrow = m0 + wm * 128 + i * 16 + q * 4;
            #pragma unroll
            for (int r = 0; r < 4; ++r)
                __builtin_nontemporal_store(acc[i][j][r] + bv,
                                            &Out[(size_t)(mrow + r) * N_DIM + n]);
        }
    }
}

// ---------------- fallback (R4, validated): direct-from-global A ----------------
__global__ __launch_bounds__(256, 2)
void qgemm_direct(const float* __restrict__ X,
                  const int* __restrict__ Wp,
                  const float* __restrict__ Sc,
                  const float* __restrict__ Bias,
                  float* __restrict__ Out)
{
    const int tid = threadIdx.x;
    const int m0 = blockIdx.x * BM;
    const int n0 = blockIdx.y * BN;
    const int lane = tid & 63;
    const int wid  = tid >> 6;
    const int wm   = wid >> 1;
    const int wn   = wid & 1;
    const int q    = lane >> 4;
    const int tt   = lane & 15;

    const int ncol = n0 + wn * 64 + tt;
    const int* bPtr = Wp + (size_t)q * N_DIM + ncol;
    const float* scPtr = Sc + ncol;
    const float* aBase = X + (size_t)(m0 + wm * 128 + tt) * K_DIM + q * 8;

    floatx4 acc[8][4];
    #pragma unroll
    for (int i = 0; i < 8; ++i)
        #pragma unroll
        for (int j = 0; j < 4; ++j)
            acc[i][j] = floatx4{0.f, 0.f, 0.f, 0.f};

    float s[4];
    for (int kt = 0; kt < NT; ++kt) {
        if ((kt & 1) == 0) {
            const float* sp = scPtr + (size_t)(kt >> 1) * N_DIM;
            #pragma unroll
            for (int j = 0; j < 4; ++j) s[j] = sp[j * 16];
        }
        const int* bp = bPtr + (size_t)kt * 8 * N_DIM;
        uint32_t wv[8];
        #pragma unroll
        for (int ks = 0; ks < 2; ++ks)
            #pragma unroll
            for (int j = 0; j < 4; ++j)
                wv[ks * 4 + j] = (uint32_t)bp[(size_t)(ks * 4) * N_DIM + j * 16];
        half8 bf[8];
        #pragma unroll
        for (int ks = 0; ks < 2; ++ks)
            #pragma unroll
            for (int j = 0; j < 4; ++j)
                bf[ks * 4 + j] = dequant_word_f16(wv[ks * 4 + j], s[j]);
        #pragma unroll
        for (int ks = 0; ks < 2; ++ks) {
            const size_t ko = (size_t)(kt * 64 + ks * 32);
            #pragma unroll
            for (int i = 0; i < 8; ++i) {
                const float* ap = aBase + (size_t)i * 16 * K_DIM + ko;
                floatx4 lo = *(const floatx4*)ap;
                floatx4 hi = *(const floatx4*)(ap + 4);
                half8 af;
                af[0] = (_Float16)lo[0]; af[1] = (_Float16)lo[1];
                af[2] = (_Float16)lo[2]; af[3] = (_Float16)lo[3];
                af[4] = (_Float16)hi[0]; af[5] = (_Float16)hi[1];
                af[6] = (_Float16)hi[2]; af[7] = (_Float16)hi[3];
                #pragma unroll
                for (int j = 0; j < 4; ++j)
                    acc[i][j] = __builtin_amdgcn_mfma_f32_16x16x32_f16(
                        af, bf[ks * 4 + j], acc[i][j], 0, 0, 0);
            }
        }
    }
    #pragma unroll
    for (int j = 0; j < 4; ++j) {
        const int n = ncol + j * 16;
        const float bv = Bias[n];
        #pragma unroll
        for (int i = 0; i < 8; ++i) {
            const int mrow = m0 + wm * 128 + i * 16 + q * 4;
            #pragma unroll
            for (int r = 0; r < 4; ++r)
                Out[(size_t)(mrow + r) * N_DIM + n] = acc[i][j][r] + bv;
        }
    }
}

extern "C" void kernel_launch(void* const* d_in, const int* in_sizes, int n_in,
                              void* d_out, int out_size, void* d_ws, size_t ws_size,
                              hipStream_t stream) {
    (void)in_sizes; (void)n_in; (void)out_size;
    const float* X    = (const float*)d_in[0];
    const int*   Wp   = (const int*)d_in[1];
    const float* Sc   = (const float*)d_in[2];
    const float* Bias = (const float*)d_in[3];
    float*       Out  = (float*)d_out;

    dim3 grid(4096 / BM, N_DIM / BN);   // (16, 86)
    const size_t needed = (size_t)4096 * K_DIM * sizeof(_Float16);  // 33.5 MB

    if (ws_size >= needed) {
        _Float16* Xh = (_Float16*)d_ws;
        cvt_kernel<<<(4096 * K_DIM) / (256 * 8), 256, 0, stream>>>(X, Xh);
        qgemm_lds<<<grid, 256, 0, stream>>>(Xh, Wp, Sc, Bias, Out);
    } else {
        qgemm_direct<<<grid, 256, 0, stream>>>(X, Wp, Sc, Bias, Out);
    }
}

// Round 6
// 584.642 us; speedup vs baseline: 1.1708x; 1.0045x over previous
//
#include <hip/hip_runtime.h>
#include <hip/hip_bf16.h>
#include <stdint.h>

#define K_DIM 4096
#define N_DIM 11008
#define BM 128            // R5: halved (was 256)
#define BN 256            // R5: doubled (was 128) -> A traffic halved
#define NT (K_DIM / 64)   // 64 K-tiles of BK=64

typedef _Float16 half8 __attribute__((ext_vector_type(8)));
typedef _Float16 half2v __attribute__((ext_vector_type(2)));
typedef float floatx4 __attribute__((ext_vector_type(4)));

typedef const uint32_t __attribute__((address_space(1)))* gas_u32p;
typedef uint32_t __attribute__((address_space(3)))* las_u32p;

// async global->LDS, 16B per lane; LDS dest = wave-uniform base + lane*16.
__device__ __forceinline__ void glds16(const void* g, void* l) {
    __builtin_amdgcn_global_load_lds((gas_u32p)g, (las_u32p)l, 16, 0, 0);
}

// ---- magic-number int4 dequant, packed-fp16 math (validated R1) ----
// (w>>s)&0x000F000F | 0x64006400 == fp16x2 {1024+q_lo, 1024+q_hi} EXACTLY.
// pk_sub 1032 -> q-8 exact; pk_mul s -> single fp16 rounding.
// Emits nibbles in order [0,4,1,5,2,6,3,7]; A pre-permuted to match.
__device__ __forceinline__ half8 dequant_word_pk(uint32_t w, half2v s2) {
    const uint32_t M = 0x000F000Fu;
    const uint32_t B = 0x64006400u;
    union { uint32_t u; half2v h; } t0, t1, t2, t3;
    t0.u = (w & M) | B;
    t1.u = ((w >> 4) & M) | B;
    t2.u = ((w >> 8) & M) | B;
    t3.u = ((w >> 12) & M) | B;
    const half2v off = {(_Float16)1032.0f, (_Float16)1032.0f};
    union { half8 h8; half2v h2[4]; } o;
    o.h2[0] = (t0.h - off) * s2;   // q0, q4
    o.h2[1] = (t1.h - off) * s2;   // q1, q5
    o.h2[2] = (t2.h - off) * s2;   // q2, q6
    o.h2[3] = (t3.h - off) * s2;   // q3, q7
    return o.h8;
}

// Old scalar dequant (kept for the validated direct fallback, natural k-order)
__device__ __forceinline__ half8 dequant_word_f16(uint32_t w, float s) {
    half8 r;
    #pragma unroll
    for (int j = 0; j < 8; ++j) {
        int q = (int)((w >> (4 * j)) & 0xFu);
        r[j] = (_Float16)((float)(q - 8) * s);
    }
    return r;
}

// ---------------- pre-pass: X fp32 -> fp16 (exact), k-permuted ----------------
// Position e of each 8-chunk holds source k = [0,4,1,5,2,6,3,7][e].
// X read once -> non-temporal loads (kept from R4: helped the pre-pass).
__global__ __launch_bounds__(256)
void cvt_kernel(const float* __restrict__ X, _Float16* __restrict__ Xh) {
    size_t idx = (size_t)blockIdx.x * 256 + threadIdx.x;   // 8 elts/thread
    size_t base = idx * 8;
    floatx4 a = __builtin_nontemporal_load((const floatx4*)(X + base));
    floatx4 b = __builtin_nontemporal_load((const floatx4*)(X + base + 4));
    half8 h;
    h[0] = (_Float16)a[0]; h[1] = (_Float16)b[0];
    h[2] = (_Float16)a[1]; h[3] = (_Float16)b[1];
    h[4] = (_Float16)a[2]; h[5] = (_Float16)b[2];
    h[6] = (_Float16)a[3]; h[7] = (_Float16)b[3];
    *(half8*)(Xh + base) = h;
}

// ------------- main: 128x256 tile, double-buffered LDS A, counted vmcnt -------------
// Structure identical to the validated R2 kernel; only geometry changed.
// 4 waves/block, each wave = 128 rows x 64 cols (8x4 fragments).
// A tile 128x64 fp16 = 16 KB/buffer; all 4 waves share it (wm removed).
__global__ __launch_bounds__(256, 2)
void qgemm_lds(const _Float16* __restrict__ Xh,
               const int* __restrict__ Wp,
               const float* __restrict__ Sc,
               const float* __restrict__ Bias,
               float* __restrict__ Out)
{
    // XOR-swizzled 16B chunks: chunk (row, c) -> slot row*8 + (c ^ (row&7)).
    __shared__ half8 As[2][BM * 8];   // 2 x 1024 chunks x 16B = 32 KB

    const int tid = threadIdx.x;

    // XCD-affine remap (round-robin model: bid&7 -> XCD). XCD x owns
    // m-blocks {4x..4x+3}: A working set/XCD = 4 x 1 MB = 4 MB = its L2.
    // Bijective: 32 m-blocks x 43 n-blocks = 1376 = 8 x 172.
    const int bid = blockIdx.y * gridDim.x + blockIdx.x;   // 0..1375
    const int xcd = bid & 7;
    const int k_r = bid >> 3;                              // 0..171
    const int m0 = (xcd * 4 + (k_r & 3)) * BM;             // m-block 0..31
    const int n0 = (k_r >> 2) * BN;                        // n-block 0..42

    const int lane = tid & 63;
    const int wid  = tid >> 6;               // 0..3
    const int wn   = wid;                    // 64-col slice within 256
    const int q    = lane >> 4;              // quad 0..3
    const int tt   = lane & 15;

    // staging: thread t, iter i (0..3) stages global chunk c of row
    // i*32 + (t>>3) into LDS slot i*256 + t;  c = (t&7) ^ ((t>>3)&7).
    const int arow = tid >> 3;               // 0..31
    const int ac   = (tid & 7) ^ (arow & 7);
    const _Float16* aSrc = Xh + (size_t)(m0 + arow) * K_DIM + ac * 8;

    // B fragment: lane's word = packed[kt*8 + ks*4 + q][ncol + j*16]
    const int ncol = n0 + wn * 64 + tt;
    const int* bPtr = Wp + (size_t)q * N_DIM + ncol;
    const float* scPtr = Sc + ncol;

    floatx4 acc[8][4];
    #pragma unroll
    for (int i = 0; i < 8; ++i)
        #pragma unroll
        for (int j = 0; j < 4; ++j)
            acc[i][j] = floatx4{0.f, 0.f, 0.f, 0.f};

    // fragment read bases (bytes): row = i*16 + tt, chunk = ks*4+q,
    // swizzled slot = (ks*4+q) ^ (tt&7)  (row&7 == tt&7).
    const int x7  = tt & 7;
    const int rb0 = tt * 128 + ((0 * 4 + q) ^ x7) * 16;
    const int rb1 = tt * 128 + ((1 * 4 + q) ^ x7) * 16;

    // ---- prologue: A-DMA tile0 -> buf0 (4 x 16B/thread), scales, B0 ----
    #pragma unroll
    for (int i = 0; i < 4; ++i)
        glds16(aSrc + (size_t)i * 32 * K_DIM,
               (char*)As[0] + (size_t)(i * 256 + tid) * 16);
    __builtin_amdgcn_sched_barrier(0);

    half2v s2[4], sn2[4];
    #pragma unroll
    for (int j = 0; j < 4; ++j) {
        _Float16 sh = (_Float16)scPtr[j * 16];   // exact: fp32 was promoted fp16
        s2[j] = (half2v){sh, sh};
    }
    uint32_t wv[8];
    #pragma unroll
    for (int ks = 0; ks < 2; ++ks)
        #pragma unroll
        for (int j = 0; j < 4; ++j)
            wv[ks * 4 + j] = (uint32_t)bPtr[(size_t)(ks * 4) * N_DIM + j * 16];

    // one-time full drain: buf0 ready for all waves after this barrier
    asm volatile("s_waitcnt vmcnt(0)" ::: "memory");
    __builtin_amdgcn_s_barrier();
    __builtin_amdgcn_sched_barrier(0);

    for (int kt = 0; kt < NT; ++kt) {
        const int cur = kt & 1;

        // commit prefetched scales at group boundary (uniform branch)
        if (kt > 0 && (kt & 1) == 0) {
            #pragma unroll
            for (int j = 0; j < 4; ++j) s2[j] = sn2[j];
        }

        // issue A DMA for NEXT tile into the other buffer (4 x 16B/thread)
        if (kt + 1 < NT) {
            #pragma unroll
            for (int i = 0; i < 4; ++i)
                glds16(aSrc + (size_t)i * 32 * K_DIM + (kt + 1) * 64,
                       (char*)As[cur ^ 1] + (size_t)(i * 256 + tid) * 16);
        }
        __builtin_amdgcn_sched_barrier(0);   // pin DMA before later loads

        // dequant current words (registers only)
        half8 bf[8];
        #pragma unroll
        for (int ks = 0; ks < 2; ++ks)
            #pragma unroll
            for (int j = 0; j < 4; ++j)
                bf[ks * 4 + j] = dequant_word_pk(wv[ks * 4 + j], s2[j]);

        // prefetch next tile's B words (+ next group's scales)
        if (kt + 1 < NT) {
            const int* bp = bPtr + (size_t)(kt + 1) * 8 * N_DIM;
            #pragma unroll
            for (int ks = 0; ks < 2; ++ks)
                #pragma unroll
                for (int j = 0; j < 4; ++j)
                    wv[ks * 4 + j] = (uint32_t)bp[(size_t)(ks * 4) * N_DIM + j * 16];
            if (kt & 1) {
                const float* sp = scPtr + (size_t)((kt + 1) >> 1) * N_DIM;
                #pragma unroll
                for (int j = 0; j < 4; ++j) {
                    _Float16 sh = (_Float16)sp[j * 16];
                    sn2[j] = (half2v){sh, sh};
                }
            }
        }

        // compute from current buffer: 2 k-steps x 8 m x 4 n = 64 MFMA
        const char* ab = (const char*)As[cur];
        #pragma unroll
        for (int ks = 0; ks < 2; ++ks) {
            const int rb = ks ? rb1 : rb0;
            #pragma unroll
            for (int i = 0; i < 8; ++i) {
                half8 af = *(const half8*)(ab + rb + i * 2048);
                #pragma unroll
                for (int j = 0; j < 4; ++j)
                    acc[i][j] = __builtin_amdgcn_mfma_f32_16x16x32_f16(
                        af, bf[ks * 4 + j], acc[i][j], 0, 0, 0);
            }
        }

        // tail sync: wait for OWN next-tile A-DMA (counted — the 8 B-word
        // loads, +4 scale loads on odd kt, issued after it stay in flight),
        // then raw barrier.
        if (kt + 1 < NT) {
            if (kt & 1) { asm volatile("s_waitcnt vmcnt(12)" ::: "memory"); }
            else        { asm volatile("s_waitcnt vmcnt(8)"  ::: "memory"); }
            __builtin_amdgcn_s_barrier();
            __builtin_amdgcn_sched_barrier(0);
        }
    }

    // epilogue: C/D layout col=lane&15, row=(lane>>4)*4+r; fp32 out + bias.
    // Plain stores (R4's nontemporal stores regressed: reverted).
    #pragma unroll
    for (int j = 0; j < 4; ++j) {
        const int n = ncol + j * 16;
        const float bv = Bias[n];
        #pragma unroll
        for (int i = 0; i < 8; ++i) {
            const int mrow = m0 + i * 16 + q * 4;
            #pragma unroll
            for (int r = 0; r < 4; ++r)
                Out[(size_t)(mrow + r) * N_DIM + n] = acc[i][j][r] + bv;
        }
    }
}

// ---------------- fallback (validated): direct-from-global A, 256x128 ----------------
__global__ __launch_bounds__(256, 2)
void qgemm_direct(const float* __restrict__ X,
                  const int* __restrict__ Wp,
                  const float* __restrict__ Sc,
                  const float* __restrict__ Bias,
                  float* __restrict__ Out)
{
    const int tid = threadIdx.x;
    const int m0 = blockIdx.x * 256;
    const int n0 = blockIdx.y * 128;
    const int lane = tid & 63;
    const int wid  = tid >> 6;
    const int wm   = wid >> 1;
    const int wn   = wid & 1;
    const int q    = lane >> 4;
    const int tt   = lane & 15;

    const int ncol = n0 + wn * 64 + tt;
    const int* bPtr = Wp + (size_t)q * N_DIM + ncol;
    const float* scPtr = Sc + ncol;
    const float* aBase = X + (size_t)(m0 + wm * 128 + tt) * K_DIM + q * 8;

    floatx4 acc[8][4];
    #pragma unroll
    for (int i = 0; i < 8; ++i)
        #pragma unroll
        for (int j = 0; j < 4; ++j)
            acc[i][j] = floatx4{0.f, 0.f, 0.f, 0.f};

    float s[4];
    for (int kt = 0; kt < NT; ++kt) {
        if ((kt & 1) == 0) {
            const float* sp = scPtr + (size_t)(kt >> 1) * N_DIM;
            #pragma unroll
            for (int j = 0; j < 4; ++j) s[j] = sp[j * 16];
        }
        const int* bp = bPtr + (size_t)kt * 8 * N_DIM;
        uint32_t wv[8];
        #pragma unroll
        for (int ks = 0; ks < 2; ++ks)
            #pragma unroll
            for (int j = 0; j < 4; ++j)
                wv[ks * 4 + j] = (uint32_t)bp[(size_t)(ks * 4) * N_DIM + j * 16];
        half8 bf[8];
        #pragma unroll
        for (int ks = 0; ks < 2; ++ks)
            #pragma unroll
            for (int j = 0; j < 4; ++j)
                bf[ks * 4 + j] = dequant_word_f16(wv[ks * 4 + j], s[j]);
        #pragma unroll
        for (int ks = 0; ks < 2; ++ks) {
            const size_t ko = (size_t)(kt * 64 + ks * 32);
            #pragma unroll
            for (int i = 0; i < 8; ++i) {
                const float* ap = aBase + (size_t)i * 16 * K_DIM + ko;
                floatx4 lo = *(const floatx4*)ap;
                floatx4 hi = *(const floatx4*)(ap + 4);
                half8 af;
                af[0] = (_Float16)lo[0]; af[1] = (_Float16)lo[1];
                af[2] = (_Float16)lo[2]; af[3] = (_Float16)lo[3];
                af[4] = (_Float16)hi[0]; af[5] = (_Float16)hi[1];
                af[6] = (_Float16)hi[2]; af[7] = (_Float16)hi[3];
                #pragma unroll
                for (int j = 0; j < 4; ++j)
                    acc[i][j] = __builtin_amdgcn_mfma_f32_16x16x32_f16(
                        af, bf[ks * 4 + j], acc[i][j], 0, 0, 0);
            }
        }
    }
    #pragma unroll
    for (int j = 0; j < 4; ++j) {
        const int n = ncol + j * 16;
        const float bv = Bias[n];
        #pragma unroll
        for (int i = 0; i < 8; ++i) {
            const int mrow = m0 + wm * 128 + i * 16 + q * 4;
            #pragma unroll
            for (int r = 0; r < 4; ++r)
                Out[(size_t)(mrow + r) * N_DIM + n] = acc[i][j][r] + bv;
        }
    }
}

extern "C" void kernel_launch(void* const* d_in, const int* in_sizes, int n_in,
                              void* d_out, int out_size, void* d_ws, size_t ws_size,
                              hipStream_t stream) {
    (void)in_sizes; (void)n_in; (void)out_size;
    const float* X    = (const float*)d_in[0];
    const int*   Wp   = (const int*)d_in[1];
    const float* Sc   = (const float*)d_in[2];
    const float* Bias = (const float*)d_in[3];
    float*       Out  = (float*)d_out;

    const size_t needed = (size_t)4096 * K_DIM * sizeof(_Float16);  // 33.5 MB

    if (ws_size >= needed) {
        _Float16* Xh = (_Float16*)d_ws;
        cvt_kernel<<<(4096 * K_DIM) / (256 * 8), 256, 0, stream>>>(X, Xh);
        dim3 grid(4096 / BM, N_DIM / BN);   // (32, 43)
        qgemm_lds<<<grid, 256, 0, stream>>>(Xh, Wp, Sc, Bias, Out);
    } else {
        dim3 gridf(4096 / 256, N_DIM / 128); // (16, 86)
        qgemm_direct<<<gridf, 256, 0, stream>>>(X, Wp, Sc, Bias, Out);
    }
}